// Round 1
// baseline (229.359 us; speedup 1.0000x reference)
//
#include <hip/hip_runtime.h>

// Sequential implicit-midpoint solve, one wave per batch element.
// y_k = y_{k-1} + DT*f_k - DT*tanh(W*(y_k+y_{k-1})/2), solved by fixed-point
// iteration (contraction rate ~0.05 => 8 iters reach f32 precision).

#define SDIM 64
#define DT_C 0.05f
#define NFP 8

__global__ __launch_bounds__(64) void rnes_seq_kernel(
    const float* __restrict__ y0,
    const float* __restrict__ forces,
    const float* __restrict__ W,
    float* __restrict__ out,
    int n, int B)
{
    const int b = blockIdx.x;
    const int p = threadIdx.x;  // lane 0..63, owns state element p and W row p

    // --- Load W row p into registers (64 VGPRs, static indices) ---
    float w[SDIM];
    {
        const float4* Wrow = reinterpret_cast<const float4*>(W + p * SDIM);
        #pragma unroll
        for (int j4 = 0; j4 < SDIM / 4; ++j4) {
            float4 v = Wrow[j4];
            w[4 * j4 + 0] = v.x;
            w[4 * j4 + 1] = v.y;
            w[4 * j4 + 2] = v.z;
            w[4 * j4 + 3] = v.w;
        }
    }

    __shared__ __align__(16) float sbuf[2][SDIM];

    float yprev = y0[b * SDIM + p];
    // out[0] = y0 (exact pass-through)
    out[b * SDIM + p] = yprev;

    int parity = 0;
    for (int k = 1; k < n; ++k) {
        const float f = forces[(size_t)k * B * SDIM + b * SDIM + p];
        const float c0 = yprev + DT_C * f;  // constant part of the update
        float y = yprev;                    // warm start

        #pragma unroll 1
        for (int it = 0; it < NFP; ++it) {
            // share s = 0.5*(y + yprev) across the wave
            sbuf[parity][p] = 0.5f * (y + yprev);
            __syncthreads();

            const float4* sv4 = reinterpret_cast<const float4*>(sbuf[parity]);
            float a0 = 0.f, a1 = 0.f, a2 = 0.f, a3 = 0.f;
            #pragma unroll
            for (int j4 = 0; j4 < SDIM / 4; ++j4) {
                float4 sv = sv4[j4];   // broadcast ds_read_b128, conflict-free
                a0 = fmaf(w[4 * j4 + 0], sv.x, a0);
                a1 = fmaf(w[4 * j4 + 1], sv.y, a1);
                a2 = fmaf(w[4 * j4 + 2], sv.z, a2);
                a3 = fmaf(w[4 * j4 + 3], sv.w, a3);
            }
            const float acc = (a0 + a1) + (a2 + a3);   // (W s)_p
            // tanh(acc) = 1 - 2/(exp(2*acc)+1); |acc| <~ 2, no overflow
            const float e = __expf(2.0f * acc);
            const float t = 1.0f - 2.0f / (e + 1.0f);
            y = c0 - DT_C * t;
            parity ^= 1;
        }

        out[(size_t)k * B * SDIM + b * SDIM + p] = y;
        yprev = y;
    }
}

extern "C" void kernel_launch(void* const* d_in, const int* in_sizes, int n_in,
                              void* d_out, int out_size, void* d_ws, size_t ws_size,
                              hipStream_t stream) {
    const float* y0     = (const float*)d_in[0];   // (B, S)
    const float* forces = (const float*)d_in[1];   // (n, B, S)
    const float* W      = (const float*)d_in[2];   // (S, S)
    float* out = (float*)d_out;                    // (n, B, S)

    const int BS = in_sizes[0];       // B * S
    const int B  = BS / SDIM;         // 128
    const int n  = in_sizes[1] / BS;  // 65

    rnes_seq_kernel<<<B, SDIM, 0, stream>>>(y0, forces, W, out, n, B);
}

// Round 2
// 65.105 us; speedup vs baseline: 3.5229x; 3.5229x over previous
//
#include <hip/hip_runtime.h>

// Sequential implicit-midpoint solve, one wave per batch element.
// y_k = y_{k-1} + DT*f_k - DT*tanh(W*(y_k+y_{k-1})/2), fixed-point iteration.
// Broadcast of the distributed state vector is done with v_readlane (register
// -> SGPR -> FMA), eliminating the LDS round-trip and barrier entirely.
// Predictor reuses previous step's converged tanh => NFP=3 suffices
// (contraction ~0.05/iter; per-step error ~1e-7 vs threshold 5e-2).

#define SDIM 64
#define DT_C 0.05f
#define NFP 3

__device__ __forceinline__ float fast_tanh(float x) {
    // tanh(x) = 1 - 2/(exp(2x)+1); |x| <~ 2 here, no overflow concerns
    const float e = __expf(2.0f * x);
    return 1.0f - 2.0f / (e + 1.0f);
}

__device__ __forceinline__ float wave_matvec(const float* __restrict__ w, float sval) {
    // u_p = sum_j w[j] * s_j where s_j lives in lane j (this wave), w = W row p.
    const int sb = __float_as_int(sval);
    float a0 = 0.f, a1 = 0.f, a2 = 0.f, a3 = 0.f;
    #pragma unroll
    for (int j = 0; j < SDIM; j += 4) {
        const float s0 = __int_as_float(__builtin_amdgcn_readlane(sb, j + 0));
        const float s1 = __int_as_float(__builtin_amdgcn_readlane(sb, j + 1));
        const float s2 = __int_as_float(__builtin_amdgcn_readlane(sb, j + 2));
        const float s3 = __int_as_float(__builtin_amdgcn_readlane(sb, j + 3));
        a0 = fmaf(w[j + 0], s0, a0);
        a1 = fmaf(w[j + 1], s1, a1);
        a2 = fmaf(w[j + 2], s2, a2);
        a3 = fmaf(w[j + 3], s3, a3);
    }
    return (a0 + a1) + (a2 + a3);
}

__global__ __launch_bounds__(64) void rnes_seq_kernel(
    const float* __restrict__ y0,
    const float* __restrict__ forces,
    const float* __restrict__ W,
    float* __restrict__ out,
    int n, int B)
{
    const int b = blockIdx.x;
    const int p = threadIdx.x;  // lane 0..63 owns state element p and W row p

    // W row p -> 64 VGPRs (static indices)
    float w[SDIM];
    {
        const float4* Wrow = reinterpret_cast<const float4*>(W + p * SDIM);
        #pragma unroll
        for (int j4 = 0; j4 < SDIM / 4; ++j4) {
            float4 v = Wrow[j4];
            w[4 * j4 + 0] = v.x;
            w[4 * j4 + 1] = v.y;
            w[4 * j4 + 2] = v.z;
            w[4 * j4 + 3] = v.w;
        }
    }

    const size_t stride = (size_t)B * SDIM;
    float yprev = y0[b * SDIM + p];
    out[b * SDIM + p] = yprev;  // out[0] = y0 pass-through

    // Initial tanh carry: t at s ~= y0 (predictor seed for step 1)
    float tcar = fast_tanh(wave_matvec(w, yprev));

    const float* fp = forces + stride + b * SDIM + p;  // &forces[1][b][p]
    float*       op = out    + stride + b * SDIM + p;  // &out[1][b][p]
    float f = *fp;

    #pragma unroll 1
    for (int k = 1; k < n; ++k) {
        // Prefetch next step's force early; its use is one full step away.
        float fnext = 0.f;
        if (k + 1 < n) fnext = fp[stride];
        fp += stride;

        const float c0 = fmaf(DT_C, f, yprev);   // yprev + DT*f
        float y = fmaf(-DT_C, tcar, c0);         // midpoint predictor
        float t = tcar;

        #pragma unroll
        for (int it = 0; it < NFP; ++it) {
            const float s = 0.5f * (y + yprev);
            const float u = wave_matvec(w, s);
            t = fast_tanh(u);
            y = fmaf(-DT_C, t, c0);
        }

        *op = y;
        op += stride;
        yprev = y;
        tcar = t;
        f = fnext;
    }
}

extern "C" void kernel_launch(void* const* d_in, const int* in_sizes, int n_in,
                              void* d_out, int out_size, void* d_ws, size_t ws_size,
                              hipStream_t stream) {
    const float* y0     = (const float*)d_in[0];   // (B, S)
    const float* forces = (const float*)d_in[1];   // (n, B, S)
    const float* W      = (const float*)d_in[2];   // (S, S)
    float* out = (float*)d_out;                    // (n, B, S)

    const int BS = in_sizes[0];       // B * S
    const int B  = BS / SDIM;         // 128
    const int n  = in_sizes[1] / BS;  // 65

    rnes_seq_kernel<<<B, SDIM, 0, stream>>>(y0, forces, W, out, n, B);
}

// Round 4
// 31.710 us; speedup vs baseline: 7.2330x; 2.0532x over previous
//
#include <hip/hip_runtime.h>

// Sequential implicit-midpoint solve, one wave per batch element.
// y_k = y_{k-1} + DT*f_k - DT*tanh(W*(y_k+y_{k-1})/2).
// Single fixed-point iteration per step (NFP=1), warm-started with the
// previous step's converged tanh (constant carry). Contraction rate
// ~0.5*DT*sigma_max(W) ~= 0.05 kills the ~1e-3 predictor error to 5e-5.
//
// Matvec u = W s via 64x v_readlane (s lives one component per lane) +
// 64x v_fma with SGPR operand; 8 accumulator chains for ILP.
// W rows are pre-scaled by 2*log2(e) so tanh(Ws) = 1 - 2/(exp2(u)+1)
// with no extra multiply on the dependent chain.

#define SDIM 64
#define DT_C 0.05f
#define WSCALE 2.8853900817779268f  // 2 / ln(2)

__device__ __forceinline__ float recip_fast(float x) {
    float r;
    asm("v_rcp_f32 %0, %1" : "=v"(r) : "v"(x));
    return r;
}

__device__ __forceinline__ float exp2_fast(float x) {
    float r;
    asm("v_exp_f32 %0, %1" : "=v"(r) : "v"(x));
    return r;
}

__device__ __forceinline__ float wave_matvec(const float* __restrict__ w, float sval) {
    // u_p = sum_j w[j] * s_j, s_j in lane j of this wave; w = (scaled) W row p.
    const int sb = __float_as_int(sval);
    float a0 = 0.f, a1 = 0.f, a2 = 0.f, a3 = 0.f;
    float a4 = 0.f, a5 = 0.f, a6 = 0.f, a7 = 0.f;
    #pragma unroll
    for (int j = 0; j < SDIM; j += 8) {
        const int b0 = __builtin_amdgcn_readlane(sb, j + 0);
        const int b1 = __builtin_amdgcn_readlane(sb, j + 1);
        const int b2 = __builtin_amdgcn_readlane(sb, j + 2);
        const int b3 = __builtin_amdgcn_readlane(sb, j + 3);
        const int b4 = __builtin_amdgcn_readlane(sb, j + 4);
        const int b5 = __builtin_amdgcn_readlane(sb, j + 5);
        const int b6 = __builtin_amdgcn_readlane(sb, j + 6);
        const int b7 = __builtin_amdgcn_readlane(sb, j + 7);
        a0 = fmaf(w[j + 0], __int_as_float(b0), a0);
        a1 = fmaf(w[j + 1], __int_as_float(b1), a1);
        a2 = fmaf(w[j + 2], __int_as_float(b2), a2);
        a3 = fmaf(w[j + 3], __int_as_float(b3), a3);
        a4 = fmaf(w[j + 4], __int_as_float(b4), a4);
        a5 = fmaf(w[j + 5], __int_as_float(b5), a5);
        a6 = fmaf(w[j + 6], __int_as_float(b6), a6);
        a7 = fmaf(w[j + 7], __int_as_float(b7), a7);
    }
    return (((a0 + a1) + (a2 + a3)) + ((a4 + a5) + (a6 + a7)));
}

__global__ __launch_bounds__(64) void rnes_seq_kernel(
    const float* __restrict__ y0,
    const float* __restrict__ forces,
    const float* __restrict__ W,
    float* __restrict__ out,
    int n, int B)
{
    const int b = blockIdx.x;
    const int p = threadIdx.x;  // lane = state component

    // W row p -> 64 VGPRs, pre-scaled by 2*log2(e)
    float w[SDIM];
    {
        const float4* Wrow = reinterpret_cast<const float4*>(W + p * SDIM);
        #pragma unroll
        for (int j4 = 0; j4 < SDIM / 4; ++j4) {
            float4 v = Wrow[j4];
            w[4 * j4 + 0] = WSCALE * v.x;
            w[4 * j4 + 1] = WSCALE * v.y;
            w[4 * j4 + 2] = WSCALE * v.z;
            w[4 * j4 + 3] = WSCALE * v.w;
        }
    }

    const size_t stride = (size_t)B * SDIM;
    float yprev = y0[b * SDIM + p];
    out[b * SDIM + p] = yprev;  // out[0] = y0 pass-through

    // Seed tanh carry at s ~= y0: t = 1 - 2/(exp2(u)+1), u = 2*log2e*(W y0)_p
    float tcar;
    {
        const float u = wave_matvec(w, yprev);
        tcar = fmaf(-2.0f, recip_fast(exp2_fast(u) + 1.0f), 1.0f);
    }

    const float* fp = forces + stride + b * SDIM + p;
    float*       op = out    + stride + b * SDIM + p;
    float f = *fp;

    #pragma unroll 1
    for (int k = 1; k < n; ++k) {
        float fnext = 0.f;
        if (k + 1 < n) fnext = fp[stride];  // prefetch, full step of slack
        fp += stride;

        const float c0 = fmaf(DT_C, f, yprev);   // yprev + DT*f
        const float y_pred = fmaf(-DT_C, tcar, c0);

        const float s = 0.5f * (y_pred + yprev);
        const float u = wave_matvec(w, s);
        const float r = recip_fast(exp2_fast(u) + 1.0f);  // 1/(e^{2Ws}+1)
        const float y = fmaf(2.0f * DT_C, r, c0 - DT_C);  // c0 - DT*tanh

        *op = y;
        op += stride;
        yprev = y;
        tcar = fmaf(-2.0f, r, 1.0f);  // tanh carry for next predictor
        f = fnext;
    }
}

extern "C" void kernel_launch(void* const* d_in, const int* in_sizes, int n_in,
                              void* d_out, int out_size, void* d_ws, size_t ws_size,
                              hipStream_t stream) {
    const float* y0     = (const float*)d_in[0];   // (B, S)
    const float* forces = (const float*)d_in[1];   // (n, B, S)
    const float* W      = (const float*)d_in[2];   // (S, S)
    float* out = (float*)d_out;                    // (n, B, S)

    const int BS = in_sizes[0];       // B * S
    const int B  = BS / SDIM;         // 128
    const int n  = in_sizes[1] / BS;  // 65

    rnes_seq_kernel<<<B, SDIM, 0, stream>>>(y0, forces, W, out, n, B);
}